// Round 14
// baseline (165.958 us; speedup 1.0000x reference)
//
#include <hip/hip_runtime.h>

// All tensors float32. Output = concat(vec[3E], dist[E], switch[E], mask[E]).
//
// R2: packed float4[N] table in d_ws -> 1 dwordx4 gather/node. 65us.
// R5: nt streaming loads; cached strided vec stores; nt dist/sw/mask.
//   Bytes at ideal (47/75MB), dur flat 65us => not BW-bound.
// R6/R11 batching curve (8/4/2 edges per thread = 72/65/66us): dur invariant
//   to wave count AND per-wave MLP => fixed-rate resource.
// R12: LDS-transposed lane-contiguous nt vec stores: 65->59us, bytes
//   UNCHANGED => the win was REQUEST COUNT (strided wave-store ~170 L2
//   requests -> 48). Model: per-XCD L2 request-rate wall.
//   Per 4-edge wave: 512 gather req (75%, irreducible: 2 random nodes/edge,
//   1 aligned 16B line each) + ~80 stream-read + ~48 store req ~= 640
//   -> ~56us modeled vs 59 measured (~95% of wall).
// R13 A/B: cached streaming loads -> 60.1-61.0us, consistent ~1.5us WORSE
//   than R12's nt (58.7-60.1). nt loads confirmed better (cached input
//   loads allocate in L2 -> eviction pressure on the gather table).
// R15/R16: ship best-measured config = R12 exactly. Every axis probed:
//   bytes (R5), wave count & per-wave MLP (R6/R11), store pattern (R12),
//   load policy (R13). Only store-request reduction moved dur. Gather
//   requests are the floor and structurally irreducible (fixed output
//   order, table >> LDS, L1 ~2% hit). R15 died in infra (acquisition
//   timeout, pre-compile) — resubmit unchanged. Predict: reproduce R12 —
//   dur 58.7-60.1, FETCH ~47.5MB, WRITE ~75MB. Arithmetic unchanged
//   (bit-exact: d<5 cliff; fp contract OFF, numpy op order, OCML sqrtf).

typedef float f32x4 __attribute__((ext_vector_type(4)));
typedef int   i32x4 __attribute__((ext_vector_type(4)));

__device__ __forceinline__ void edge_math(
    float dx0, float dx1, float dx2,
    float sh0, float sh1, float sh2, const float c[9],
    float& v0, float& v1, float& v2, float& dist, float& sw, float& mk)
{
#pragma clang fp contract(off)
    float m0 = sh0 * c[0]; m0 = m0 + sh1 * c[3]; m0 = m0 + sh2 * c[6];
    float m1 = sh0 * c[1]; m1 = m1 + sh1 * c[4]; m1 = m1 + sh2 * c[7];
    float m2 = sh0 * c[2]; m2 = m2 + sh1 * c[5]; m2 = m2 + sh2 * c[8];
    v0 = dx0 + m0; v1 = dx1 + m1; v2 = dx2 + m2;
    float q = v0 * v0; q = q + v1 * v1; q = q + v2 * v2;
    dist = sqrtf(q);
    bool m = dist < 5.0f;
    float cv = cosf(dist * 0.62831853f);   // f32(pi/5)
    sw = m ? (0.5f * cv + 0.5f) : 0.0f;
    mk = m ? 1.0f : 0.0f;
}

// ---- prepass: coords[N,3] -> packed float4[N] in ws ----
// cached stores: the table is the one thing we WANT resident in L2/L3.
__global__ __launch_bounds__(256) void pack_coords_kernel(
    const float* __restrict__ coords, float4* __restrict__ packed, int n_nodes)
{
    int i = blockIdx.x * blockDim.x + threadIdx.x;
    if (i >= n_nodes) return;
    const float* p = coords + 3 * (size_t)i;
    packed[i] = make_float4(p[0], p[1], p[2], 0.0f);
}

// ---- main kernel: 4 edges/thread, nt streaming loads,
//      LDS-transposed lane-contiguous nt vec stores (R12 config) ----
__global__ __launch_bounds__(256) void GraphProcessor_64012192579962_kernel(
    const float4* __restrict__ packed,  // [N] xyz_
    const int*   __restrict__ esrc,     // [E]
    const int*   __restrict__ edst,     // [E]
    const float* __restrict__ shifts,   // [E,3]
    const float* __restrict__ cells,    // [9]
    float* __restrict__ out_vec,        // [E,3]
    float* __restrict__ out_dist,       // [E]
    float* __restrict__ out_sw,         // [E]
    float* __restrict__ out_mask,       // [E]
    int n_quads, int n_edges)
{
#pragma clang fp contract(off)
    // per-wave transpose buffer: 64 rows x 20 floats (pad 12->20: 16B-aligned
    // rows, 80B stride -> 2-way bank aliasing only, which is free).
    __shared__ float lds[4][64 * 20];

    const int t     = blockIdx.x * blockDim.x + threadIdx.x;
    const int lane  = threadIdx.x & 63;
    const int wslot = threadIdx.x >> 6;

    float c[9];
#pragma unroll
    for (int i = 0; i < 9; ++i) c[i] = cells[i];   // uniform -> scalar loads

    const bool active = t < n_quads;
    const int  e0     = 4 * t;
    const bool full   = active && (e0 + 3 < n_edges);
    const unsigned long long fm = __ballot(full);
    const bool wave_full = (fm == 0xFFFFFFFFFFFFFFFFull);

    float v[12];

    if (full) {
        // streaming, read-once -> nontemporal (R13 A/B: nt beats cached
        // by ~1.5us — cached input loads evict the gather table from L2)
        i32x4 ss = __builtin_nontemporal_load((const i32x4*)esrc + t);
        i32x4 dd = __builtin_nontemporal_load((const i32x4*)edst + t);
        const f32x4* shp = (const f32x4*)(shifts + 12 * (size_t)t);
        f32x4 h0 = __builtin_nontemporal_load(shp + 0);
        f32x4 h1 = __builtin_nontemporal_load(shp + 1);
        f32x4 h2 = __builtin_nontemporal_load(shp + 2);

        // issue all 8 gathers before any compute (cached: table L2-resident)
        float4 s0 = packed[ss.x], s1 = packed[ss.y], s2 = packed[ss.z], s3 = packed[ss.w];
        float4 d0 = packed[dd.x], d1 = packed[dd.y], d2 = packed[dd.z], d3 = packed[dd.w];

        float di[4], sw[4], mk[4];
        edge_math(d0.x - s0.x, d0.y - s0.y, d0.z - s0.z, h0.x, h0.y, h0.z, c, v[0], v[1],  v[2],  di[0], sw[0], mk[0]);
        edge_math(d1.x - s1.x, d1.y - s1.y, d1.z - s1.z, h0.w, h1.x, h1.y, c, v[3], v[4],  v[5],  di[1], sw[1], mk[1]);
        edge_math(d2.x - s2.x, d2.y - s2.y, d2.z - s2.z, h1.z, h1.w, h2.x, c, v[6], v[7],  v[8],  di[2], sw[2], mk[2]);
        edge_math(d3.x - s3.x, d3.y - s3.y, d3.z - s3.z, h2.y, h2.z, h2.w, c, v[9], v[10], v[11], di[3], sw[3], mk[3]);

        // dist/sw/mask: lane-contiguous full lines -> nt.
        f32x4 od = { di[0], di[1], di[2], di[3] };
        f32x4 os = { sw[0], sw[1], sw[2], sw[3] };
        f32x4 om = { mk[0], mk[1], mk[2], mk[3] };
        __builtin_nontemporal_store(od, (f32x4*)out_dist + t);
        __builtin_nontemporal_store(os, (f32x4*)out_sw   + t);
        __builtin_nontemporal_store(om, (f32x4*)out_mask + t);

        if (wave_full) {
            // stage this thread's 12 vec floats into its padded LDS row
            float* row = &lds[wslot][lane * 20];
            f32x4 w0 = { v[0], v[1],  v[2],  v[3]  };
            f32x4 w1 = { v[4], v[5],  v[6],  v[7]  };
            f32x4 w2 = { v[8], v[9],  v[10], v[11] };
            *(f32x4*)(row + 0) = w0;
            *(f32x4*)(row + 4) = w1;
            *(f32x4*)(row + 8) = w2;
        }
    }

    __builtin_amdgcn_sched_barrier(0);   // keep ds_writes before ds_reads

    if (full && wave_full) {
        // wave-synchronous readback: 192 float4s of the wave's 768-float
        // region, lane-contiguous per instruction -> nt dwordx4 stores
        // (16 L2 granule-requests per wave-instr instead of ~56 strided).
        const size_t w = (size_t)blockIdx.x * 4 + wslot;
        float* base = out_vec + w * 768;
#pragma unroll
        for (int k = 0; k < 3; ++k) {
            const int f   = k * 256 + 4 * lane;   // region float offset
            const int u   = f / 12;               // source row
            const int col = f % 12;               // {0,4,8}: never crosses row
            f32x4 val = *(const f32x4*)&lds[wslot][u * 20 + col];
            __builtin_nontemporal_store(val, (f32x4*)(base + f));
        }
    } else if (full) {
        // partial wave: cached strided stores (rare tail only)
        float4* ov = (float4*)(out_vec + 12 * (size_t)t);
        ov[0] = make_float4(v[0], v[1], v[2],  v[3]);
        ov[1] = make_float4(v[4], v[5], v[6],  v[7]);
        ov[2] = make_float4(v[8], v[9], v[10], v[11]);
    }

    if (active && !full) {
        for (int e = e0; e < n_edges; ++e) {
            float4 s = packed[esrc[e]], d = packed[edst[e]];
            float v0, v1, v2, di, sw, mk;
            edge_math(d.x - s.x, d.y - s.y, d.z - s.z,
                      shifts[3 * (size_t)e], shifts[3 * (size_t)e + 1],
                      shifts[3 * (size_t)e + 2], c, v0, v1, v2, di, sw, mk);
            out_vec[3 * (size_t)e]     = v0;
            out_vec[3 * (size_t)e + 1] = v1;
            out_vec[3 * (size_t)e + 2] = v2;
            out_dist[e] = di;
            out_sw[e]   = sw;
            out_mask[e] = mk;
        }
    }
}

// ---- fallback (ws too small): 12B struct gathers straight from coords ----
struct F3 { float x, y, z; };

__global__ __launch_bounds__(256) void GraphProcessor_fallback_kernel(
    const float* __restrict__ coords,
    const int*   __restrict__ esrc,
    const int*   __restrict__ edst,
    const float* __restrict__ shifts,
    const float* __restrict__ cells,
    float* __restrict__ out_vec,
    float* __restrict__ out_dist,
    float* __restrict__ out_sw,
    float* __restrict__ out_mask,
    int n_quads, int n_edges)
{
#pragma clang fp contract(off)
    int t = blockIdx.x * blockDim.x + threadIdx.x;
    if (t >= n_quads) return;

    float c[9];
#pragma unroll
    for (int i = 0; i < 9; ++i) c[i] = cells[i];

    const F3* nodes = (const F3*)coords;
    const int e0 = 4 * t;

    if (e0 + 3 < n_edges) {
        i32x4 ss = __builtin_nontemporal_load((const i32x4*)esrc + t);
        i32x4 dd = __builtin_nontemporal_load((const i32x4*)edst + t);
        const f32x4* shp = (const f32x4*)(shifts + 12 * (size_t)t);
        f32x4 h0 = __builtin_nontemporal_load(shp + 0);
        f32x4 h1 = __builtin_nontemporal_load(shp + 1);
        f32x4 h2 = __builtin_nontemporal_load(shp + 2);

        F3 s0 = nodes[ss.x], s1 = nodes[ss.y], s2 = nodes[ss.z], s3 = nodes[ss.w];
        F3 d0 = nodes[dd.x], d1 = nodes[dd.y], d2 = nodes[dd.z], d3 = nodes[dd.w];

        float v[12], di[4], sw[4], mk[4];
        edge_math(d0.x - s0.x, d0.y - s0.y, d0.z - s0.z, h0.x, h0.y, h0.z, c, v[0], v[1],  v[2],  di[0], sw[0], mk[0]);
        edge_math(d1.x - s1.x, d1.y - s1.y, d1.z - s1.z, h0.w, h1.x, h1.y, c, v[3], v[4],  v[5],  di[1], sw[1], mk[1]);
        edge_math(d2.x - s2.x, d2.y - s2.y, d2.z - s2.z, h1.z, h1.w, h2.x, c, v[6], v[7],  v[8],  di[2], sw[2], mk[2]);
        edge_math(d3.x - s3.x, d3.y - s3.y, d3.z - s3.z, h2.y, h2.z, h2.w, c, v[9], v[10], v[11], di[3], sw[3], mk[3]);

        float4* ov = (float4*)(out_vec + 12 * (size_t)t);
        ov[0] = make_float4(v[0], v[1], v[2],  v[3]);
        ov[1] = make_float4(v[4], v[5], v[6],  v[7]);
        ov[2] = make_float4(v[8], v[9], v[10], v[11]);

        f32x4 od = { di[0], di[1], di[2], di[3] };
        f32x4 os = { sw[0], sw[1], sw[2], sw[3] };
        f32x4 om = { mk[0], mk[1], mk[2], mk[3] };
        __builtin_nontemporal_store(od, (f32x4*)out_dist + t);
        __builtin_nontemporal_store(os, (f32x4*)out_sw   + t);
        __builtin_nontemporal_store(om, (f32x4*)out_mask + t);
    } else {
        for (int e = e0; e < n_edges; ++e) {
            F3 s = nodes[esrc[e]], d = nodes[edst[e]];
            float v0, v1, v2, di, sw, mk;
            edge_math(d.x - s.x, d.y - s.y, d.z - s.z,
                      shifts[3 * (size_t)e], shifts[3 * (size_t)e + 1],
                      shifts[3 * (size_t)e + 2], c, v0, v1, v2, di, sw, mk);
            out_vec[3 * (size_t)e]     = v0;
            out_vec[3 * (size_t)e + 1] = v1;
            out_vec[3 * (size_t)e + 2] = v2;
            out_dist[e] = di;
            out_sw[e]   = sw;
            out_mask[e] = mk;
        }
    }
}

extern "C" void kernel_launch(void* const* d_in, const int* in_sizes, int n_in,
                              void* d_out, int out_size, void* d_ws, size_t ws_size,
                              hipStream_t stream) {
    const float* coords = (const float*)d_in[0];
    const int*   esrc   = (const int*)d_in[1];
    const int*   edst   = (const int*)d_in[2];
    const float* shifts = (const float*)d_in[3];
    const float* cells  = (const float*)d_in[4];

    const int N = in_sizes[0] / 3;  // n_nodes
    const int E = in_sizes[1];      // n_edges

    float* out      = (float*)d_out;
    float* out_vec  = out;                     // [E,3]
    float* out_dist = out + 3 * (size_t)E;     // [E]
    float* out_sw   = out_dist + E;            // [E]
    float* out_mask = out_sw + E;              // [E]

    const int n_quads = (E + 3) / 4;
    dim3 block(256);
    dim3 grid((n_quads + 255) / 256);

    if (ws_size >= (size_t)N * sizeof(float4)) {
        float4* packed = (float4*)d_ws;
        pack_coords_kernel<<<(N + 255) / 256, 256, 0, stream>>>(coords, packed, N);
        GraphProcessor_64012192579962_kernel<<<grid, block, 0, stream>>>(
            packed, esrc, edst, shifts, cells,
            out_vec, out_dist, out_sw, out_mask, n_quads, E);
    } else {
        GraphProcessor_fallback_kernel<<<grid, block, 0, stream>>>(
            coords, esrc, edst, shifts, cells,
            out_vec, out_dist, out_sw, out_mask, n_quads, E);
    }
}